// Round 2
// baseline (41.294 us; speedup 1.0000x reference)
//
#include <hip/hip_runtime.h>
#include <math.h>

// TokenChoiceRouter: B=8, T=8192, D=512.
// d_out (float32 flat): [selected B*max_k][gate_weights B*max_k][raw_logits B*T][aux][z]
// ws: [se f32 x4096][sg f32 x4096][cnt int x4096]  (per 16-token chunk partials)

#define TT 8192
#define BB 8
#define CHUNK 16               // tokens per chunk (= per wave in K1)
#define NCHUNK 4096            // 65536 / 16
#define CPR 512                // chunks per row
#define BPR 128                // K2 blocks per row (4 chunks = 64 tokens each)

__global__ __launch_bounds__(256) void k1_logits(
    const float* __restrict__ x, const float* __restrict__ W,
    float* __restrict__ logits,
    float* __restrict__ ws_se, float* __restrict__ ws_sg, int* __restrict__ ws_cnt)
{
    const int lane = threadIdx.x & 63;
    const int wid  = threadIdx.x >> 6;
    const int wave = blockIdx.x * 4 + wid;         // 0..4095, one 16-token chunk

    const float4* wp = reinterpret_cast<const float4*>(W + lane * 8);
    const float4 w0 = wp[0], w1 = wp[1];

    float se_c = 0.f, sg_c = 0.f;
    int   cnt_c = 0;

    #pragma unroll
    for (int g = 0; g < 2; ++g) {
        const int tok0 = wave * CHUNK + g * 8;
        const float4* xp = reinterpret_cast<const float4*>(
            x + (size_t)tok0 * 512 + lane * 8);

        double acc[8];
        #pragma unroll
        for (int j = 0; j < 8; ++j) {
            float4 a0 = xp[j * 128];
            float4 a1 = xp[j * 128 + 1];
            acc[j] = (double)a0.x * w0.x + (double)a0.y * w0.y
                   + (double)a0.z * w0.z + (double)a0.w * w0.w
                   + (double)a1.x * w1.x + (double)a1.y * w1.y
                   + (double)a1.z * w1.z + (double)a1.w * w1.w;
        }

        // Stage 1: per token, sum residue classes mod 8 (xor 8,16,32).
        #pragma unroll
        for (int j = 0; j < 8; ++j) {
            acc[j] += __shfl_xor(acc[j], 8, 64);
            acc[j] += __shfl_xor(acc[j], 16, 64);
            acc[j] += __shfl_xor(acc[j], 32, 64);
        }
        // Select acc[lane>>3] with compile-time indices (no scratch).
        double sA = (lane & 8)  ? acc[1] : acc[0];
        double sB = (lane & 8)  ? acc[3] : acc[2];
        double sC = (lane & 8)  ? acc[5] : acc[4];
        double sD = (lane & 8)  ? acc[7] : acc[6];
        double sE = (lane & 16) ? sB : sA;
        double sF = (lane & 16) ? sD : sC;
        double s  = (lane & 32) ? sF : sE;
        // Stage 2: combine the 8 residues (xor 1,2,4) — finalizes 8 tokens at once.
        s += __shfl_xor(s, 1, 64);
        s += __shfl_xor(s, 2, 64);
        s += __shfl_xor(s, 4, 64);
        // Lane 8a+b (all b) now holds token (tok0+a)'s full dot.

        const float lg = (float)s;
        if ((lane & 7) == 0) logits[tok0 + (lane >> 3)] = lg;

        // Per-group stats (every lane in group a holds token a's value).
        float e  = expf(lg);
        float sg = 1.f / (1.f + expf(-lg));
        // Sum across the 8 groups: xor 8,16,32 picks one lane per group.
        e  += __shfl_xor(e, 8, 64);  e  += __shfl_xor(e, 16, 64);  e  += __shfl_xor(e, 32, 64);
        sg += __shfl_xor(sg, 8, 64); sg += __shfl_xor(sg, 16, 64); sg += __shfl_xor(sg, 32, 64);
        unsigned long long bal = __ballot(lg >= 0.f);   // each token counted 8x
        se_c  += e;
        sg_c  += sg;
        cnt_c += (int)(__popcll(bal) >> 3);
    }

    if (lane == 0) {
        ws_se[wave]  = se_c;
        ws_sg[wave]  = sg_c;
        ws_cnt[wave] = cnt_c;
    }
}

__global__ __launch_bounds__(256) void k2_finish(
    const float* __restrict__ logits,
    const int* __restrict__ ws_cnt, const float* __restrict__ ws_se,
    const float* __restrict__ ws_sg,
    float* __restrict__ out_sel, float* __restrict__ out_gw,
    float* __restrict__ out_aux, float* __restrict__ out_z, int max_k)
{
    const int tid  = threadIdx.x;
    const int lane = tid & 63;
    const int wid  = tid >> 6;

    if (blockIdx.x == BB * BPR) {
        // ---- scalar losses ----
        __shared__ float sred[256];
        __shared__ float rowse[BB];
        for (int r = 0; r < BB; ++r) {
            float p = 0.f;
            for (int i = tid; i < CPR; i += 256) p += ws_se[r * CPR + i];
            sred[tid] = p; __syncthreads();
            for (int s = 128; s > 0; s >>= 1) {
                if (tid < s) sred[tid] += sred[tid + s];
                __syncthreads();
            }
            if (tid == 0) rowse[r] = sred[0];
            __syncthreads();
        }
        float p = 0.f;
        for (int i = tid; i < NCHUNK; i += 256) p += ws_sg[i];
        sred[tid] = p; __syncthreads();
        for (int s = 128; s > 0; s >>= 1) {
            if (tid < s) sred[tid] += sred[tid + s];
            __syncthreads();
        }
        if (tid == 0) {
            float zz = 0.f;
            for (int r = 0; r < BB; ++r) { float z = logf(rowse[r]); zz += z * z; }
            *out_z = 0.001f * zz / (float)BB;
            float m = sred[0] / (float)(BB * TT);
            *out_aux = 0.01f * m * (1.f - m);
        }
        return;
    }

    const int row  = blockIdx.x >> 7;   // /BPR
    const int part = blockIdx.x & 127;  // %BPR

    __shared__ int s_pref[CPR];
    __shared__ int s_wsum[4];
    __shared__ int s_lnz[4];

    // Scan this row's 512 chunk counts (2 per thread).
    const int c0 = ws_cnt[row * CPR + 2 * tid];
    const int c1 = ws_cnt[row * CPR + 2 * tid + 1];
    const int v  = c0 + c1;
    int inc = v;
    #pragma unroll
    for (int off = 1; off < 64; off <<= 1) {
        int n = __shfl_up(inc, off, 64);
        if (lane >= off) inc += n;
    }
    if (lane == 63) s_wsum[wid] = inc;
    int lnz = (c1 > 0) ? (2 * tid + 1) : ((c0 > 0) ? (2 * tid) : -1);
    #pragma unroll
    for (int off = 32; off > 0; off >>= 1)
        lnz = max(lnz, __shfl_xor(lnz, off, 64));
    if (lane == 0) s_lnz[wid] = lnz;
    __syncthreads();
    int woff = 0;
    for (int w = 0; w < wid; ++w) woff += s_wsum[w];
    const int cnt = s_wsum[0] + s_wsum[1] + s_wsum[2] + s_wsum[3];
    const int excl = woff + inc - v;
    s_pref[2 * tid]     = excl;
    s_pref[2 * tid + 1] = excl + c0;
    const int lastnz = max(max(s_lnz[0], s_lnz[1]), max(s_lnz[2], s_lnz[3]));
    __syncthreads();

    // This block's 64 tokens (wave 0 only).
    if (tid < 64) {
        const int tloc = part * 64 + tid;
        const float lg = logits[row * TT + tloc];
        const bool sel = (lg >= 0.f);
        unsigned long long bal = __ballot(sel);
        const int cib = tid >> 4;                 // chunk within block (0..3)
        unsigned long long below = bal & ((1ull << tid) - 1ull);
        below &= (0xFFFFull << (cib * 16));
        const int pos = s_pref[part * 4 + cib] + (int)__popcll(below);
        if (sel) {
            out_sel[(size_t)row * max_k + pos] = (float)tloc;
            out_gw [(size_t)row * max_k + pos] = 1.f / (1.f + expf(-lg));
        }
    }

    // Pad region [cnt, max_k): clamp to last selected (row-empty -> token 0).
    if (part == BPR - 1) {
        int tok_last = 0;
        if (cnt > 0) {
            const int cL = lastnz;
            for (int j = CHUNK - 1; j >= 0; --j) {
                float lg = logits[row * TT + cL * CHUNK + j];
                if (lg >= 0.f) { tok_last = cL * CHUNK + j; break; }
            }
        }
        const float lgl = logits[row * TT + tok_last];
        const float gw_last = 1.f / (1.f + expf(-lgl));
        for (int k = cnt + tid; k < max_k; k += 256) {
            out_sel[(size_t)row * max_k + k] = (float)tok_last;
            out_gw [(size_t)row * max_k + k] = gw_last;
        }
    }
}

extern "C" void kernel_launch(void* const* d_in, const int* in_sizes, int n_in,
                              void* d_out, int out_size, void* d_ws, size_t ws_size,
                              hipStream_t stream)
{
    const float* x = (const float*)d_in[0];
    const float* W = (const float*)d_in[1];

    const int D  = in_sizes[1];          // 512
    const int BT = in_sizes[0] / D;      // 65536
    const int max_k = (out_size - BT - 2) / (2 * BB);

    float* out        = (float*)d_out;
    float* out_sel    = out;
    float* out_gw     = out + (size_t)BB * max_k;
    float* out_logits = out + (size_t)2 * BB * max_k;
    float* out_aux    = out + (size_t)2 * BB * max_k + BT;
    float* out_z      = out_aux + 1;

    float* ws_se  = (float*)d_ws;
    float* ws_sg  = ws_se + NCHUNK;
    int*   ws_cnt = (int*)(ws_sg + NCHUNK);

    // K1: 4096 waves, 16 tokens each; logits + per-chunk stats.
    k1_logits<<<1024, 256, 0, stream>>>(x, W, out_logits, ws_se, ws_sg, ws_cnt);

    // K2: 8 rows x 128 blocks (compaction/fill/pad) + 1 block (scalars).
    k2_finish<<<BB * BPR + 1, 256, 0, stream>>>(out_logits, ws_cnt, ws_se, ws_sg,
                                                out_sel, out_gw, out_aux, out_z,
                                                max_k);
}